// Round 7
// baseline (33.360 us; speedup 1.0000x reference)
//
#include <hip/hip_runtime.h>

// Problem constants (from reference)
#define B_      4
#define L_      512
#define S_      100
#define NG_     19
#define GS_     5
#define VOCAB_  6
#define HID_    512
#define HPOOL_  4
#define D_      64
#define ALL_    256      // HPOOL * D
#define FIREH_  32
#define MAXDIST_ 20.0f

typedef float f32x2 __attribute__((ext_vector_type(2)));
typedef float f32x4 __attribute__((ext_vector_type(4)));

#define NROWS_  (B_ * L_)             // 2048
// ws layout (floats): [0..99] bias, [128..128+24*512) W2 (q = v*4+h major, d minor)

// ---------------------------------------------------------------------------
// K1: precompute FIRE bias (100 values) and W2[v*4+h][d] = value_emb slice @ ffn_w
// ---------------------------------------------------------------------------
__global__ __launch_bounds__(128) void prep_kernel(
    const float* __restrict__ dist,      // (100,)
    const float* __restrict__ value_emb, // (6,256)
    const float* __restrict__ ffn_w,     // (256,512)
    const float* __restrict__ fire_c,
    const float* __restrict__ fire_w1,
    const float* __restrict__ fire_w2,
    float* __restrict__ bias_out,        // ws + 0
    float* __restrict__ W2_out)          // ws + 128
{
  const int b = blockIdx.x;
  const int t = threadIdx.x;
  if (b < VOCAB_ * HPOOL_ * 4) {
    const int q   = b >> 2;            // 0..23
    const int col = (b & 3) * 128 + t; // 0..511
    const int v = q >> 2, h = q & 3;
    float acc = 0.f;
#pragma unroll
    for (int k = 0; k < D_; ++k)
      acc = fmaf(value_emb[v * ALL_ + h * D_ + k],
                 ffn_w[(h * D_ + k) * HID_ + col], acc);
    W2_out[q * HID_ + col] = acc;
  } else if (t < S_) {
    const float c = fmaxf(fire_c[0], 0.f);
    const float denom = logf(fmaf(c, MAXDIST_, 1.f));
    const float rel = logf(fmaf(c, dist[t], 1.f)) / denom;
    float acc = 0.f;
#pragma unroll
    for (int i = 0; i < FIREH_; ++i) {
      const float x = rel * fire_w1[i];
      acc = fmaf(x / (1.f + __expf(-x)), fire_w2[i], acc);   // silu
    }
    bias_out[t] = acc;
  }
}

// ---------------------------------------------------------------------------
// K2: main. One block per TWO (b,l) rows; 256 threads.
// Thread t: row r = t>>7, cols 4*(t&127)..+3  (f32x4 everywhere).
// Rationale: per-wave LDS broadcast count is the binding pipe (114
// ds_read_b128/wave); covering a row with 2 waves instead of 4 halves the
// CU-wide LDS traffic (43.8K -> 21.9K cy/CU), putting stores back on top.
// ---------------------------------------------------------------------------
static __device__ __forceinline__ f32x4 fm4(float s, f32x4 w, f32x4 a) {
  a.x = fmaf(s, w.x, a.x);
  a.y = fmaf(s, w.y, a.y);
  a.z = fmaf(s, w.z, a.z);
  a.w = fmaf(s, w.w, a.w);
  return a;
}

#define QB4(C, BASE)                    \
  a0 = fm4(C.x, w2r[BASE + 0], a0);     \
  a1 = fm4(C.y, w2r[BASE + 1], a1);     \
  a2 = fm4(C.z, w2r[BASE + 2], a2);     \
  a3 = fm4(C.w, w2r[BASE + 3], a3);

__global__ __launch_bounds__(256) void main_kernel(
    const int*   __restrict__ ids,       // (B*L, 100)
    const float* __restrict__ attn_w,    // (6,4)
    const float* __restrict__ embed_tab, // (6,512)
    const float* __restrict__ ffn_b,     // (512,)
    const float* __restrict__ bias,      // (100,) from ws
    const float* __restrict__ W2,        // (24,512) from ws
    float* __restrict__ out)             // (B*L, 24, 512)
{
  const int blk = blockIdx.x;            // 0..1023
  const int t   = threadIdx.x;
  const int bl0 = blk * 2;

  __shared__ int   s_ids[2 * S_];
  __shared__ float s_bias[S_];
  __shared__ float s_aw[VOCAB_ * HPOOL_];
  __shared__ __align__(16) float s_cw[2][NG_][24];

  // --- staging (independent loads, all in flight together) ---
  if (t < 2 * S_) s_ids[t] = ids[bl0 * S_ + t];
  if (t < S_)     s_bias[t] = bias[t];
  if (t < VOCAB_ * HPOOL_) s_aw[t] = attn_w[t];

  // hoist W2/ffn_b loads before the barrier: latency hides under phase A
  const int r  = t >> 7;                 // 0/1 : which row this thread serves
  const int c4 = (t & 127) * 4;          // col base
  f32x4 w2r[24];
#pragma unroll
  for (int q = 0; q < 24; ++q)
    w2r[q] = *(const f32x4*)&W2[q * HID_ + c4];
  const f32x4 bb = *(const f32x4*)&ffn_b[c4];

#pragma unroll
  for (int i = t; i < 2 * NG_ * 24; i += 256) ((float*)s_cw)[i] = 0.f;
  __syncthreads();

  // --- phase A: both rows' softmaxes, 152 threads ---
  if (t < 2 * NG_ * HPOOL_) {
    const int pr = (t >= 76) ? 1 : 0;
    const int u  = t - 76 * pr;
    const int n  = u >> 2, h = u & 3;
    int idg[GS_]; float p[GS_]; float m = -1e30f;
#pragma unroll
    for (int g = 0; g < GS_; ++g) {
      idg[g] = s_ids[pr * S_ + n * GS_ + g];
      p[g] = s_aw[idg[g] * HPOOL_ + h] + s_bias[n * GS_ + g];
      m = fmaxf(m, p[g]);
    }
    float s = 0.f;
#pragma unroll
    for (int g = 0; g < GS_; ++g) { p[g] = __expf(p[g] - m); s += p[g]; }
    const float inv = 1.f / s;
#pragma unroll
    for (int g = 0; g < GS_; ++g)
      s_cw[pr][n][idg[g] * HPOOL_ + h] += p[g] * inv;  // exclusive ownership
  }
  __syncthreads();

  float* op = out + (size_t)(bl0 + r) * 24 * HID_ + c4;

  // --- singles FIRST: independent stores prime the store pipe ---
#pragma unroll
  for (int j = 0; j < 5; ++j) {
    const int id = s_ids[r * S_ + NG_ * GS_ + j];
    *(f32x4*)(op + (NG_ + j) * HID_) =
        *(const f32x4*)&embed_tab[id * HID_ + c4];
  }

  // --- phase B: 4 partial f32x4 accumulators (16 independent FMA chains) ---
  for (int n = 0; n < NG_; ++n) {
    const f32x4* cw4 = (const f32x4*)s_cw[r][n];
    const f32x4 c0 = cw4[0], c1 = cw4[1], c2 = cw4[2],
                c3 = cw4[3], c4v = cw4[4], c5 = cw4[5];
    f32x4 a0 = bb;
    f32x4 a1 = {0.f, 0.f, 0.f, 0.f};
    f32x4 a2 = {0.f, 0.f, 0.f, 0.f};
    f32x4 a3 = {0.f, 0.f, 0.f, 0.f};
    QB4(c0, 0) QB4(c1, 4) QB4(c2, 8) QB4(c3, 12) QB4(c4v, 16) QB4(c5, 20)
    f32x4 acc;
    acc.x = (a0.x + a1.x) + (a2.x + a3.x);
    acc.y = (a0.y + a1.y) + (a2.y + a3.y);
    acc.z = (a0.z + a1.z) + (a2.z + a3.z);
    acc.w = (a0.w + a1.w) + (a2.w + a3.w);
    *(f32x4*)(op + n * HID_) = acc;
  }
}

// ---------------------------------------------------------------------------
extern "C" void kernel_launch(void* const* d_in, const int* in_sizes, int n_in,
                              void* d_out, int out_size, void* d_ws, size_t ws_size,
                              hipStream_t stream) {
  const int*   src_ids = (const int*)  d_in[0];
  const float* dist    = (const float*)d_in[1];
  const float* attn_w  = (const float*)d_in[2];
  const float* valemb  = (const float*)d_in[3];
  const float* ffn_w   = (const float*)d_in[4];
  const float* ffn_b   = (const float*)d_in[5];
  const float* emb_tab = (const float*)d_in[6];
  const float* fire_c  = (const float*)d_in[7];
  const float* fire_w1 = (const float*)d_in[8];
  const float* fire_w2 = (const float*)d_in[9];

  float* out  = (float*)d_out;
  float* ws   = (float*)d_ws;
  float* bias = ws;         // 100 floats
  float* W2   = ws + 128;   // 24*512 floats (16B-aligned)

  hipLaunchKernelGGL(prep_kernel, dim3(97), dim3(128), 0, stream,
                     dist, valemb, ffn_w, fire_c, fire_w1, fire_w2, bias, W2);
  hipLaunchKernelGGL(main_kernel, dim3(NROWS_ / 2), dim3(256), 0, stream,
                     src_ids, attn_w, emb_tab, ffn_b, bias, W2, out);
}

// Round 8
// 32.274 us; speedup vs baseline: 1.0336x; 1.0336x over previous
//
#include <hip/hip_runtime.h>

// Problem constants (from reference)
#define B_      4
#define L_      512
#define S_      100
#define NG_     19
#define GS_     5
#define VOCAB_  6
#define HID_    512
#define HPOOL_  4
#define D_      64
#define ALL_    256      // HPOOL * D
#define FIREH_  32
#define MAXDIST_ 20.0f

typedef float f32x2 __attribute__((ext_vector_type(2)));
typedef float f32x4 __attribute__((ext_vector_type(4)));

#define NROWS_  (B_ * L_)             // 2048
// ws layout (floats): [0..99] bias, [128..128+24*512) W2 (q = v*4+h major, d minor)

// ---------------------------------------------------------------------------
// K1: precompute FIRE bias (100 values) and W2[v*4+h][d] = value_emb slice @ ffn_w
// ---------------------------------------------------------------------------
__global__ __launch_bounds__(128) void prep_kernel(
    const float* __restrict__ dist,      // (100,)
    const float* __restrict__ value_emb, // (6,256)
    const float* __restrict__ ffn_w,     // (256,512)
    const float* __restrict__ fire_c,
    const float* __restrict__ fire_w1,
    const float* __restrict__ fire_w2,
    float* __restrict__ bias_out,        // ws + 0
    float* __restrict__ W2_out)          // ws + 128
{
  const int b = blockIdx.x;
  const int t = threadIdx.x;
  if (b < VOCAB_ * HPOOL_ * 4) {
    const int q   = b >> 2;            // 0..23
    const int col = (b & 3) * 128 + t; // 0..511
    const int v = q >> 2, h = q & 3;
    float acc = 0.f;
#pragma unroll
    for (int k = 0; k < D_; ++k)
      acc = fmaf(value_emb[v * ALL_ + h * D_ + k],
                 ffn_w[(h * D_ + k) * HID_ + col], acc);
    W2_out[q * HID_ + col] = acc;
  } else if (t < S_) {
    const float c = fmaxf(fire_c[0], 0.f);
    const float denom = logf(fmaf(c, MAXDIST_, 1.f));
    const float rel = logf(fmaf(c, dist[t], 1.f)) / denom;
    float acc = 0.f;
#pragma unroll
    for (int i = 0; i < FIREH_; ++i) {
      const float x = rel * fire_w1[i];
      acc = fmaf(x / (1.f + __expf(-x)), fire_w2[i], acc);   // silu
    }
    bias_out[t] = acc;
  }
}

// ---------------------------------------------------------------------------
// K2: main. 512 blocks x 512 threads, FOUR rows per block.
// Geometry: 8 waves/block x 2 blocks/CU = 16 waves/CU, grid 512 = exactly
// 2 blocks/CU -> SINGLE cohort (no ragged tail — the unmodeled cost of
// R2/R7). launch_bounds(512,4) caps VGPR at 128 so 2 blocks/CU is real.
// Thread t: row r = t>>7, cols 4*(t&127)..+3 (f32x4: halves LDS traffic per
// column vs f32x2 — LDS 72cy < store-drain 94cy per work unit -> store-bound).
// ---------------------------------------------------------------------------
static __device__ __forceinline__ f32x4 fm4(float s, f32x4 w, f32x4 a) {
  a.x = fmaf(s, w.x, a.x);
  a.y = fmaf(s, w.y, a.y);
  a.z = fmaf(s, w.z, a.z);
  a.w = fmaf(s, w.w, a.w);
  return a;
}

__global__ __launch_bounds__(512, 4) void main_kernel(
    const int*   __restrict__ ids,       // (B*L, 100)
    const float* __restrict__ attn_w,    // (6,4)
    const float* __restrict__ embed_tab, // (6,512)
    const float* __restrict__ ffn_b,     // (512,)
    const float* __restrict__ bias,      // (100,) from ws
    const float* __restrict__ W2,        // (24,512) from ws
    float* __restrict__ out)             // (B*L, 24, 512)
{
  const int blk = blockIdx.x;            // 0..511
  const int t   = threadIdx.x;
  const int bl0 = blk * 4;

  __shared__ int   s_ids[4 * S_];
  __shared__ float s_bias[S_];
  __shared__ float s_aw[VOCAB_ * HPOOL_];
  __shared__ __align__(16) float s_cw[4][NG_][24];

  // --- staging (independent loads, all in flight together) ---
  if (t < 4 * S_) s_ids[t] = ids[bl0 * S_ + t];
  if (t >= 400 && t < 500) s_bias[t - 400] = bias[t - 400];
  if (t >= 488) s_aw[t - 488] = attn_w[t - 488];

  // hoist W2/ffn_b loads before the barrier: latency hides under phase A
  const int r  = t >> 7;                 // 0..3 : row within block (wave-uniform)
  const int c4 = (t & 127) * 4;          // col base
  f32x4 w2r[24];
#pragma unroll
  for (int q = 0; q < 24; ++q)
    w2r[q] = *(const f32x4*)&W2[q * HID_ + c4];
  const f32x4 bb = *(const f32x4*)&ffn_b[c4];

#pragma unroll
  for (int i = t; i < 4 * NG_ * 24; i += 512) ((float*)s_cw)[i] = 0.f;
  __syncthreads();

  // --- phase A: 4 rows x 76 softmax tasks = 304 threads ---
  if (t < 4 * NG_ * HPOOL_) {
    const int pr = t / 76;
    const int u  = t - pr * 76;
    const int n  = u >> 2, h = u & 3;
    int idg[GS_]; float p[GS_]; float m = -1e30f;
#pragma unroll
    for (int g = 0; g < GS_; ++g) {
      idg[g] = s_ids[pr * S_ + n * GS_ + g];
      p[g] = s_aw[idg[g] * HPOOL_ + h] + s_bias[n * GS_ + g];
      m = fmaxf(m, p[g]);
    }
    float s = 0.f;
#pragma unroll
    for (int g = 0; g < GS_; ++g) { p[g] = __expf(p[g] - m); s += p[g]; }
    const float inv = 1.f / s;
#pragma unroll
    for (int g = 0; g < GS_; ++g)
      s_cw[pr][n][idg[g] * HPOOL_ + h] += p[g] * inv;  // exclusive ownership
  }
  __syncthreads();

  float* op = out + (size_t)(bl0 + r) * 24 * HID_ + c4;

  // --- singles FIRST: independent stores prime the store pipe ---
#pragma unroll
  for (int j = 0; j < 5; ++j) {
    const int id = s_ids[r * S_ + NG_ * GS_ + j];
    *(f32x4*)(op + (NG_ + j) * HID_) =
        *(const f32x4*)&embed_tab[id * HID_ + c4];
  }

  // --- phase B: single acc chain (R6: chain length neutral; saves VGPR) ---
  for (int n = 0; n < NG_; ++n) {
    const f32x4* cw4 = (const f32x4*)s_cw[r][n];
    f32x4 acc = bb;
#pragma unroll
    for (int k = 0; k < 6; ++k) {
      const f32x4 c = cw4[k];              // wave-uniform broadcast
      acc = fm4(c.x, w2r[k * 4 + 0], acc);
      acc = fm4(c.y, w2r[k * 4 + 1], acc);
      acc = fm4(c.z, w2r[k * 4 + 2], acc);
      acc = fm4(c.w, w2r[k * 4 + 3], acc);
    }
    *(f32x4*)(op + n * HID_) = acc;
  }
}

// ---------------------------------------------------------------------------
extern "C" void kernel_launch(void* const* d_in, const int* in_sizes, int n_in,
                              void* d_out, int out_size, void* d_ws, size_t ws_size,
                              hipStream_t stream) {
  const int*   src_ids = (const int*)  d_in[0];
  const float* dist    = (const float*)d_in[1];
  const float* attn_w  = (const float*)d_in[2];
  const float* valemb  = (const float*)d_in[3];
  const float* ffn_w   = (const float*)d_in[4];
  const float* ffn_b   = (const float*)d_in[5];
  const float* emb_tab = (const float*)d_in[6];
  const float* fire_c  = (const float*)d_in[7];
  const float* fire_w1 = (const float*)d_in[8];
  const float* fire_w2 = (const float*)d_in[9];

  float* out  = (float*)d_out;
  float* ws   = (float*)d_ws;
  float* bias = ws;         // 100 floats
  float* W2   = ws + 128;   // 24*512 floats (16B-aligned)

  hipLaunchKernelGGL(prep_kernel, dim3(97), dim3(128), 0, stream,
                     dist, valemb, ffn_w, fire_c, fire_w1, fire_w2, bias, W2);
  hipLaunchKernelGGL(main_kernel, dim3(NROWS_ / 4), dim3(512), 0, stream,
                     src_ids, attn_w, emb_tab, ffn_b, bias, W2, out);
}